// Round 1
// baseline (5342.156 us; speedup 1.0000x reference)
//
#include <hip/hip_runtime.h>

// DGMRF forward, L layers, T=16 channels.
// Layer math (factored): S[d] = sum_{e: dst(e)=d} x[src(e)]  (unweighted!)
//   x_new[n] = sw * x[n] * deg[n]^dp + nw * S[n] * deg[n]^(dp-1) + bias
// where dp = sigmoid(gamma[l]), sw = exp(alpha1[l]), nw = sw * tanh(alpha1[l]).
// deg = OUT-degree over edge_index[0] (matches reference's degree(edge_index[0])).

#define TCH 16

__global__ void k_deg(const int* __restrict__ src, int* __restrict__ deg, int E) {
    int e = blockIdx.x * blockDim.x + threadIdx.x;
    if (e < E) atomicAdd(&deg[src[e]], 1);
}

// x [T][N] channel-major -> xt [N][T] node-major
__global__ void k_tin(const float* __restrict__ x, float* __restrict__ xt, int N) {
    int n = blockIdx.x * blockDim.x + threadIdx.x;
    if (n >= N) return;
    float v[TCH];
#pragma unroll
    for (int t = 0; t < TCH; ++t) v[t] = x[(size_t)t * N + n];
    float4* o = reinterpret_cast<float4*>(xt + (size_t)n * TCH);
    o[0] = make_float4(v[0],  v[1],  v[2],  v[3]);
    o[1] = make_float4(v[4],  v[5],  v[6],  v[7]);
    o[2] = make_float4(v[8],  v[9],  v[10], v[11]);
    o[3] = make_float4(v[12], v[13], v[14], v[15]);
}

// one thread per edge: gather 64B at src, 16 f32 atomics at dst
__global__ void k_scatter(const int* __restrict__ src, const int* __restrict__ dst,
                          const float* __restrict__ xt, float* __restrict__ S, int E) {
    int e = blockIdx.x * blockDim.x + threadIdx.x;
    if (e >= E) return;
    int s = src[e], d = dst[e];
    const float4* xs = reinterpret_cast<const float4*>(xt + (size_t)s * TCH);
    float4 a = xs[0], b = xs[1], c = xs[2], w = xs[3];
    float* o = S + (size_t)d * TCH;
    atomicAdd(o + 0,  a.x); atomicAdd(o + 1,  a.y); atomicAdd(o + 2,  a.z); atomicAdd(o + 3,  a.w);
    atomicAdd(o + 4,  b.x); atomicAdd(o + 5,  b.y); atomicAdd(o + 6,  b.z); atomicAdd(o + 7,  b.w);
    atomicAdd(o + 8,  c.x); atomicAdd(o + 9,  c.y); atomicAdd(o + 10, c.z); atomicAdd(o + 11, c.w);
    atomicAdd(o + 12, w.x); atomicAdd(o + 13, w.y); atomicAdd(o + 14, w.z); atomicAdd(o + 15, w.w);
}

// per-node combine. last==0: write back into xt (in-place, node-major).
// last==1: write transposed straight to out [T][N] (coalesced per-t).
__global__ void k_combine(float* __restrict__ xt, const float* __restrict__ S,
                          const int* __restrict__ deg,
                          const float* __restrict__ alpha1, const float* __restrict__ gamma,
                          const float* __restrict__ bias, int l, int N,
                          int last, float* __restrict__ out) {
    int n = blockIdx.x * blockDim.x + threadIdx.x;
    if (n >= N) return;
    float a1 = alpha1[l];
    float g  = gamma[l];
    float bi = bias[l];
    float dp = 1.0f / (1.0f + expf(-g));   // sigmoid
    float sw = expf(a1);
    float nw = sw * tanhf(a1);
    float ld = logf((float)deg[n]);        // matches reference log(deg); deg==0 -> -inf like ref
    float wd = expf(dp * ld);              // deg^dp
    float wn = expf((dp - 1.0f) * ld);     // deg^(dp-1)
    float cs = sw * wd;                    // coeff on x
    float cn = nw * wn;                    // coeff on S

    float4* xv = reinterpret_cast<float4*>(xt + (size_t)n * TCH);
    const float4* sv = reinterpret_cast<const float4*>(S + (size_t)n * TCH);
    float r[TCH];
#pragma unroll
    for (int q = 0; q < 4; ++q) {
        float4 xq = xv[q];
        float4 sq = sv[q];
        r[q * 4 + 0] = cs * xq.x + cn * sq.x + bi;
        r[q * 4 + 1] = cs * xq.y + cn * sq.y + bi;
        r[q * 4 + 2] = cs * xq.z + cn * sq.z + bi;
        r[q * 4 + 3] = cs * xq.w + cn * sq.w + bi;
    }
    if (last) {
#pragma unroll
        for (int t = 0; t < TCH; ++t) out[(size_t)t * N + n] = r[t];
    } else {
#pragma unroll
        for (int q = 0; q < 4; ++q)
            xv[q] = make_float4(r[q * 4 + 0], r[q * 4 + 1], r[q * 4 + 2], r[q * 4 + 3]);
    }
}

extern "C" void kernel_launch(void* const* d_in, const int* in_sizes, int n_in,
                              void* d_out, int out_size, void* d_ws, size_t ws_size,
                              hipStream_t stream) {
    const float* x      = (const float*)d_in[0];
    const int*   ei     = (const int*)d_in[1];
    const float* alpha1 = (const float*)d_in[2];
    // d_in[3] = alpha2: UNUSED (reference's alpha2 property returns alpha1)
    const float* gamma  = (const float*)d_in[4];
    const float* bias   = (const float*)d_in[5];
    float* out = (float*)d_out;

    const int N = in_sizes[0] / TCH;
    const int E = in_sizes[1] / 2;
    const int L = in_sizes[2];
    const int* src = ei;
    const int* dst = ei + E;

    // workspace layout
    char* ws = (char*)d_ws;
    size_t o0 = 0;                                   // deg: N * 4
    size_t o1 = ((size_t)N * 4 + 255) & ~(size_t)255; // xt: N*16*4
    size_t o2 = o1 + (((size_t)N * TCH * 4 + 255) & ~(size_t)255); // S: N*16*4
    int*   deg = (int*)(ws + o0);
    float* xt  = (float*)(ws + o1);
    float* S   = (float*)(ws + o2);

    const int BLK = 256;
    dim3 gE((E + BLK - 1) / BLK), gN((N + BLK - 1) / BLK), b(BLK);

    hipMemsetAsync(deg, 0, (size_t)N * 4, stream);
    k_deg<<<gE, b, 0, stream>>>(src, deg, E);
    k_tin<<<gN, b, 0, stream>>>(x, xt, N);

    for (int l = 0; l < L; ++l) {
        hipMemsetAsync(S, 0, (size_t)N * TCH * 4, stream);
        k_scatter<<<gE, b, 0, stream>>>(src, dst, xt, S, E);
        int last = (l == L - 1) ? 1 : 0;
        k_combine<<<gN, b, 0, stream>>>(xt, S, deg, alpha1, gamma, bias, l, N, last, out);
    }
}

// Round 2
// 857.267 us; speedup vs baseline: 6.2316x; 6.2316x over previous
//
#include <hip/hip_runtime.h>

// DGMRF forward, L layers, T=16 channels — CSR pull formulation.
// Layer math (factored): S[d] = sum_{e: dst(e)=d} x[src(e)]  (unweighted)
//   x_new[n] = sw * x[n] * deg[n]^dp + nw * S[n] * deg[n]^(dp-1) + bias
// dp = sigmoid(gamma[l]), sw = exp(alpha1[l]), nw = sw * tanh(alpha1[l]).
// deg = OUT-degree over edge_index[0]. S computed by PULL over dst-CSR
// (built per call) -> no f32 atomics at all.

#define TCH 16
#define SCAN_T 1024

// fused degree counts: out-degree (math) + in-degree (CSR sizing)
__global__ void k_counts(const int* __restrict__ src, const int* __restrict__ dst,
                         int* __restrict__ deg_out, int* __restrict__ indeg, int E) {
    int e = blockIdx.x * blockDim.x + threadIdx.x;
    if (e >= E) return;
    atomicAdd(&deg_out[src[e]], 1);
    atomicAdd(&indeg[dst[e]], 1);
}

// x [T][N] channel-major -> xt [N][T] node-major
__global__ void k_tin(const float* __restrict__ x, float* __restrict__ xt, int N) {
    int n = blockIdx.x * blockDim.x + threadIdx.x;
    if (n >= N) return;
    float v[TCH];
#pragma unroll
    for (int t = 0; t < TCH; ++t) v[t] = x[(size_t)t * N + n];
    float4* o = reinterpret_cast<float4*>(xt + (size_t)n * TCH);
    o[0] = make_float4(v[0],  v[1],  v[2],  v[3]);
    o[1] = make_float4(v[4],  v[5],  v[6],  v[7]);
    o[2] = make_float4(v[8],  v[9],  v[10], v[11]);
    o[3] = make_float4(v[12], v[13], v[14], v[15]);
}

// single-block exclusive scan of indeg -> row_ptr (N+1) and cursor copy
__global__ void k_scan(const int* __restrict__ indeg, int* __restrict__ row_ptr,
                       int* __restrict__ cursor, int N) {
    __shared__ int ssum[SCAN_T];
    int tid = threadIdx.x;
    int chunk = (N + SCAN_T - 1) / SCAN_T;
    int beg = tid * chunk;
    int end = beg + chunk; if (end > N) end = N;
    int s = 0;
    for (int i = beg; i < end; ++i) s += indeg[i];
    ssum[tid] = s;
    __syncthreads();
    // Hillis-Steele inclusive scan over 1024 partials
    for (int off = 1; off < SCAN_T; off <<= 1) {
        int v = (tid >= off) ? ssum[tid - off] : 0;
        __syncthreads();
        if (tid >= off) ssum[tid] += v;
        __syncthreads();
    }
    int run = (tid == 0) ? 0 : ssum[tid - 1];
    for (int i = beg; i < end; ++i) {
        row_ptr[i] = run;
        cursor[i]  = run;
        run += indeg[i];
    }
    if (beg < N && end == N) row_ptr[N] = run;
}

// fill adjacency: adj[pos] = src for each edge, bucketed by dst
__global__ void k_fill(const int* __restrict__ src, const int* __restrict__ dst,
                       int* __restrict__ cursor, int* __restrict__ adj, int E) {
    int e = blockIdx.x * blockDim.x + threadIdx.x;
    if (e >= E) return;
    int p = atomicAdd(&cursor[dst[e]], 1);
    adj[p] = src[e];
}

// fused pull + combine. 4 threads per node, one float4 quarter each.
// last==0: write xout node-major. last==1: write out [T][N].
__global__ void k_layer(const float* __restrict__ xin, float* __restrict__ xout,
                        const int* __restrict__ row_ptr, const int* __restrict__ adj,
                        const int* __restrict__ deg_out,
                        const float* __restrict__ a1p, const float* __restrict__ gp,
                        const float* __restrict__ bp, int l, int N,
                        int last, float* __restrict__ out) {
    int tt = blockIdx.x * blockDim.x + threadIdx.x;
    int n = tt >> 2;
    int q = tt & 3;
    if (n >= N) return;
    float a1 = a1p[l], g = gp[l], bi = bp[l];
    float dp = 1.0f / (1.0f + expf(-g));
    float sw = expf(a1);
    float nw = sw * tanhf(a1);

    int b = row_ptr[n], e2 = row_ptr[n + 1];
    float4 acc = make_float4(0.f, 0.f, 0.f, 0.f);
    for (int i = b; i < e2; ++i) {
        int s = adj[i];
        float4 xs = reinterpret_cast<const float4*>(xin + (size_t)s * TCH)[q];
        acc.x += xs.x; acc.y += xs.y; acc.z += xs.z; acc.w += xs.w;
    }

    float ld = logf((float)deg_out[n]);
    float cs = sw * expf(dp * ld);            // coeff on x
    float cn = nw * expf((dp - 1.0f) * ld);   // coeff on neighbor sum

    float4 xq = reinterpret_cast<const float4*>(xin + (size_t)n * TCH)[q];
    float4 r;
    r.x = cs * xq.x + cn * acc.x + bi;
    r.y = cs * xq.y + cn * acc.y + bi;
    r.z = cs * xq.z + cn * acc.z + bi;
    r.w = cs * xq.w + cn * acc.w + bi;

    if (last) {
        int t0 = q * 4;
        out[(size_t)(t0 + 0) * N + n] = r.x;
        out[(size_t)(t0 + 1) * N + n] = r.y;
        out[(size_t)(t0 + 2) * N + n] = r.z;
        out[(size_t)(t0 + 3) * N + n] = r.w;
    } else {
        reinterpret_cast<float4*>(xout + (size_t)n * TCH)[q] = r;
    }
}

extern "C" void kernel_launch(void* const* d_in, const int* in_sizes, int n_in,
                              void* d_out, int out_size, void* d_ws, size_t ws_size,
                              hipStream_t stream) {
    const float* x      = (const float*)d_in[0];
    const int*   ei     = (const int*)d_in[1];
    const float* alpha1 = (const float*)d_in[2];
    // d_in[3] = alpha2: UNUSED (reference's alpha2 property returns alpha1)
    const float* gamma  = (const float*)d_in[4];
    const float* bias   = (const float*)d_in[5];
    float* out = (float*)d_out;

    const int N = in_sizes[0] / TCH;
    const int E = in_sizes[1] / 2;
    const int L = in_sizes[2];
    const int* src = ei;
    const int* dst = ei + E;

    // workspace layout (256B aligned)
    auto align = [](size_t v) { return (v + 255) & ~(size_t)255; };
    char* ws = (char*)d_ws;
    size_t off = 0;
    int* deg_out = (int*)(ws + off); off += align((size_t)N * 4);
    int* indeg   = (int*)(ws + off); off += align((size_t)N * 4);
    int* row_ptr = (int*)(ws + off); off += align(((size_t)N + 1) * 4);
    int* cursor  = (int*)(ws + off); off += align((size_t)N * 4);
    int* adj     = (int*)(ws + off); off += align((size_t)E * 4);
    float* xt0   = (float*)(ws + off); off += align((size_t)N * TCH * 4);
    float* xt1   = (float*)(ws + off); off += align((size_t)N * TCH * 4);

    const int BLK = 256;
    dim3 gE((E + BLK - 1) / BLK), gN((N + BLK - 1) / BLK);
    dim3 gN4(((size_t)N * 4 + BLK - 1) / BLK), b(BLK);

    // deg_out and indeg are adjacent -> one memset
    hipMemsetAsync(deg_out, 0, align((size_t)N * 4) + (size_t)N * 4, stream);
    k_counts<<<gE, b, 0, stream>>>(src, dst, deg_out, indeg, E);
    k_tin<<<gN, b, 0, stream>>>(x, xt0, N);
    k_scan<<<dim3(1), dim3(SCAN_T), 0, stream>>>(indeg, row_ptr, cursor, N);
    k_fill<<<gE, b, 0, stream>>>(src, dst, cursor, adj, E);

    float* xin = xt0;
    float* xo  = xt1;
    for (int l = 0; l < L; ++l) {
        int last = (l == L - 1) ? 1 : 0;
        k_layer<<<gN4, b, 0, stream>>>(xin, xo, row_ptr, adj, deg_out,
                                       alpha1, gamma, bias, l, N, last, out);
        float* tmp = xin; xin = xo; xo = tmp;
    }
}

// Round 3
// 450.113 us; speedup vs baseline: 11.8685x; 1.9046x over previous
//
#include <hip/hip_runtime.h>

// DGMRF forward, L layers, T=16 channels — padded-bucket CSR pull.
// Layer math (factored): S[d] = sum_{e: dst(e)=d} x[src(e)]  (unweighted)
//   x_new[n] = sw * x[n] * deg[n]^dp + nw * S[n] * deg[n]^(dp-1) + bias
// dp = sigmoid(gamma[l]), sw = exp(alpha1[l]), nw = sw * tanh(alpha1[l]).
// deg = OUT-degree over edge_index[0].
// Build: one fused pass — rank atomic doubles as in-degree count; no scan,
// no separate indeg histogram. Overflow (rank>=CAP) goes to a spill list
// handled by a tiny atomic fix-up kernel per layer (0 entries for this data).

#define TCH 16
#define SPILL_CAP 65536

// fused build: out-degree histogram + padded-bucket adjacency fill
__global__ void k_build(const int* __restrict__ src, const int* __restrict__ dst,
                        int* __restrict__ deg_out, int* __restrict__ cnt,
                        int* __restrict__ spill_n, int* __restrict__ spill,
                        int* __restrict__ adj, int E, int CAP) {
    int e = blockIdx.x * blockDim.x + threadIdx.x;
    if (e >= E) return;
    int s = src[e], d = dst[e];
    atomicAdd(&deg_out[s], 1);
    int r = atomicAdd(&cnt[d], 1);
    if (r < CAP) {
        adj[(size_t)d * CAP + r] = s;
    } else {
        int p = atomicAdd(spill_n, 1);
        if (p < SPILL_CAP) { spill[2 * p] = d; spill[2 * p + 1] = s; }
    }
}

// x [T][N] channel-major -> xt [N][T] node-major
__global__ void k_tin(const float* __restrict__ x, float* __restrict__ xt, int N) {
    int n = blockIdx.x * blockDim.x + threadIdx.x;
    if (n >= N) return;
    float v[TCH];
#pragma unroll
    for (int t = 0; t < TCH; ++t) v[t] = x[(size_t)t * N + n];
    float4* o = reinterpret_cast<float4*>(xt + (size_t)n * TCH);
    o[0] = make_float4(v[0],  v[1],  v[2],  v[3]);
    o[1] = make_float4(v[4],  v[5],  v[6],  v[7]);
    o[2] = make_float4(v[8],  v[9],  v[10], v[11]);
    o[3] = make_float4(v[12], v[13], v[14], v[15]);
}

// fused pull + combine. 4 threads per node, one float4 quarter each.
// last==0: write xout node-major. last==1: write out [T][N].
__global__ void k_layer(const float* __restrict__ xin, float* __restrict__ xout,
                        const int* __restrict__ cnt, const int* __restrict__ adj,
                        const int* __restrict__ deg_out,
                        const float* __restrict__ a1p, const float* __restrict__ gp,
                        const float* __restrict__ bp, int l, int N, int CAP,
                        int last, float* __restrict__ out) {
    int tt = blockIdx.x * blockDim.x + threadIdx.x;
    int n = tt >> 2;
    int q = tt & 3;
    if (n >= N) return;
    float a1 = a1p[l], g = gp[l], bi = bp[l];
    float dp = 1.0f / (1.0f + expf(-g));
    float sw = expf(a1);
    float nw = sw * tanhf(a1);

    int m = cnt[n]; if (m > CAP) m = CAP;
    const int* row = adj + (size_t)n * CAP;
    float4 acc = make_float4(0.f, 0.f, 0.f, 0.f);
    int i = 0;
    for (; i + 1 < m; i += 2) {               // 2-wide for load ILP
        int s0 = row[i], s1 = row[i + 1];
        float4 x0 = reinterpret_cast<const float4*>(xin + (size_t)s0 * TCH)[q];
        float4 x1 = reinterpret_cast<const float4*>(xin + (size_t)s1 * TCH)[q];
        acc.x += x0.x; acc.y += x0.y; acc.z += x0.z; acc.w += x0.w;
        acc.x += x1.x; acc.y += x1.y; acc.z += x1.z; acc.w += x1.w;
    }
    if (i < m) {
        int s0 = row[i];
        float4 x0 = reinterpret_cast<const float4*>(xin + (size_t)s0 * TCH)[q];
        acc.x += x0.x; acc.y += x0.y; acc.z += x0.z; acc.w += x0.w;
    }

    float ld = logf((float)deg_out[n]);
    float cs = sw * expf(dp * ld);            // coeff on x
    float cn = nw * expf((dp - 1.0f) * ld);   // coeff on neighbor sum

    float4 xq = reinterpret_cast<const float4*>(xin + (size_t)n * TCH)[q];
    float4 r;
    r.x = cs * xq.x + cn * acc.x + bi;
    r.y = cs * xq.y + cn * acc.y + bi;
    r.z = cs * xq.z + cn * acc.z + bi;
    r.w = cs * xq.w + cn * acc.w + bi;

    if (last) {
        int t0 = q * 4;
        out[(size_t)(t0 + 0) * N + n] = r.x;
        out[(size_t)(t0 + 1) * N + n] = r.y;
        out[(size_t)(t0 + 2) * N + n] = r.z;
        out[(size_t)(t0 + 3) * N + n] = r.w;
    } else {
        reinterpret_cast<float4*>(xout + (size_t)n * TCH)[q] = r;
    }
}

// fix-up for spilled edges (normally zero entries -> immediate exit)
__global__ void k_spill(const int* __restrict__ spill_n, const int* __restrict__ spill,
                        const float* __restrict__ xin, float* __restrict__ xout,
                        const int* __restrict__ deg_out,
                        const float* __restrict__ a1p, const float* __restrict__ gp,
                        int l, int N, int last, float* __restrict__ out) {
    int total = *spill_n; if (total > SPILL_CAP) total = SPILL_CAP;
    int stride = gridDim.x * blockDim.x;
    float a1 = a1p[l], g = gp[l];
    float dp = 1.0f / (1.0f + expf(-g));
    float nw = expf(a1) * tanhf(a1);
    for (int p = blockIdx.x * blockDim.x + threadIdx.x; p < total; p += stride) {
        int d = spill[2 * p], s = spill[2 * p + 1];
        float cn = nw * expf((dp - 1.0f) * logf((float)deg_out[d]));
#pragma unroll
        for (int t = 0; t < TCH; ++t) {
            float v = cn * xin[(size_t)s * TCH + t];
            if (last) atomicAdd(&out[(size_t)t * N + d], v);
            else      atomicAdd(&xout[(size_t)d * TCH + t], v);
        }
    }
}

extern "C" void kernel_launch(void* const* d_in, const int* in_sizes, int n_in,
                              void* d_out, int out_size, void* d_ws, size_t ws_size,
                              hipStream_t stream) {
    const float* x      = (const float*)d_in[0];
    const int*   ei     = (const int*)d_in[1];
    const float* alpha1 = (const float*)d_in[2];
    // d_in[3] = alpha2: UNUSED (reference's alpha2 property returns alpha1)
    const float* gamma  = (const float*)d_in[4];
    const float* bias   = (const float*)d_in[5];
    float* out = (float*)d_out;

    const int N = in_sizes[0] / TCH;
    const int E = in_sizes[1] / 2;
    const int L = in_sizes[2];
    const int* src = ei;
    const int* dst = ei + E;

    // workspace layout (256B aligned)
    auto align = [](size_t v) { return (v + 255) & ~(size_t)255; };
    char* ws = (char*)d_ws;
    size_t off = 0;
    int* deg_out = (int*)(ws + off); off += align((size_t)N * 4);
    int* cnt     = (int*)(ws + off); off += align((size_t)N * 4);
    int* spill_n = (int*)(ws + off); off += 256;
    size_t zero_bytes = off;                    // deg_out, cnt, spill_n contiguous
    float* xt0   = (float*)(ws + off); off += align((size_t)N * TCH * 4);
    float* xt1   = (float*)(ws + off); off += align((size_t)N * TCH * 4);
    int* spill   = (int*)(ws + off); off += align((size_t)SPILL_CAP * 8);
    int* adj     = (int*)(ws + off);
    // capacity per bucket from remaining workspace, capped at 96 (Poisson(32)
    // tail beyond 96 is ~1e-19 for this graph)
    int CAP = 96;
    size_t rem = (ws_size > off) ? (ws_size - off) : 0;
    size_t cap_fit = rem / ((size_t)N * 4);
    if ((size_t)CAP > cap_fit) CAP = (int)cap_fit;
    if (CAP < 1) CAP = 1;

    const int BLK = 256;
    dim3 gE((E + BLK - 1) / BLK), gN((N + BLK - 1) / BLK);
    dim3 gN4(((size_t)N * 4 + BLK - 1) / BLK), b(BLK);

    hipMemsetAsync(deg_out, 0, zero_bytes, stream);
    k_build<<<gE, b, 0, stream>>>(src, dst, deg_out, cnt, spill_n, spill, adj, E, CAP);
    k_tin<<<gN, b, 0, stream>>>(x, xt0, N);

    float* xin = xt0;
    float* xo  = xt1;
    for (int l = 0; l < L; ++l) {
        int last = (l == L - 1) ? 1 : 0;
        k_layer<<<gN4, b, 0, stream>>>(xin, xo, cnt, adj, deg_out,
                                       alpha1, gamma, bias, l, N, CAP, last, out);
        k_spill<<<dim3(64), b, 0, stream>>>(spill_n, spill, xin, xo, deg_out,
                                            alpha1, gamma, l, N, last, out);
        float* tmp = xin; xin = xo; xo = tmp;
    }
}